// Round 6
// baseline (415.549 us; speedup 1.0000x reference)
//
#include <hip/hip_runtime.h>
#include <math.h>

// EncoderBlock: B=8, N=1024, EMB=768, HEADS=8, DHEAD=96
// R14 = R13 resubmit (R5 bench failed with a container-acquisition infra
//       error; kernel re-audited: workspace byte-total identical to the
//       passing R12, no divergent barriers, split-K mapping bijective).
//   - prep_kernel: cvt + 4 weight transposes fused into ONE dispatch.
//   - FF2 split-K x4: 768 blocks x 12 K-tiles = 3 clean CU rounds (was 192
//     blocks x 48 tiles at 75% CU util). fp32 partials overlay the dead
//     xb..attn_o workspace region; LN2 sums res + 3 partials.
//   - LayerNorm vectorized (float4 / bf16x4).
//   - GEMM engine (R12 single-barrier triple-buffer), attention: unchanged.

typedef __bf16 bf16_t;
typedef __bf16 bf16x4 __attribute__((ext_vector_type(4)));
typedef __bf16 bf16x8 __attribute__((ext_vector_type(8)));
typedef float f32x4 __attribute__((ext_vector_type(4)));

#define EMB   768
#define HEADS 8
#define DHEAD 96
#define BATCH 8
#define SEQ   1024
#define ROWS  (BATCH * SEQ)   // 8192
#define ACTN  ((size_t)ROWS * EMB)  // 6291456

__device__ __forceinline__ void load16_lds(const bf16_t* g, bf16_t* l) {
    __builtin_amdgcn_global_load_lds(
        (__attribute__((address_space(1))) unsigned int*)g,
        (__attribute__((address_space(3))) unsigned int*)l,
        16, 0, 0);
}

// ---------------------------------------------------------------- fused prep
// Sections (1D grid, 256 thr):
//   [0,768)        : x fp32 -> xb bf16 (float4/bf16x4)
//   [768,3072)     : qkvr permuted transpose  (96 x 24 tiles)
//   [3072,3648)    : w_proj transpose         (24 x 24)
//   [3648,5952)    : w_ff1 transpose          (96 x 24)
//   [5952,8256)    : w_ff2 transpose          (24 x 96)

__device__ __forceinline__ void tile_transpose(
    const float* __restrict__ in, bf16_t* __restrict__ out,
    int K, int N, int n0, int k0, float (*t)[33], int tx, int ty0)
{
#pragma unroll
    for (int i = 0; i < 4; i++) {
        int ty = ty0 + 8 * i;
        t[ty][tx] = in[(size_t)(k0 + ty) * N + n0 + tx];
    }
    __syncthreads();
#pragma unroll
    for (int i = 0; i < 4; i++) {
        int ty = ty0 + 8 * i;
        out[(size_t)(n0 + ty) * K + k0 + tx] = (bf16_t)t[tx][ty];
    }
}

__global__ __launch_bounds__(256) void prep_kernel(
    const float* __restrict__ x, bf16_t* __restrict__ xb,
    const float* __restrict__ w_qkvr, bf16_t* __restrict__ wqkvrT,
    const float* __restrict__ w_proj, bf16_t* __restrict__ wprojT,
    const float* __restrict__ w_ff1, bf16_t* __restrict__ wff1T,
    const float* __restrict__ w_ff2, bf16_t* __restrict__ wff2T)
{
    __shared__ float t[32][33];
    int id = blockIdx.x;
    if (id < 768) {                      // cvt x -> xb
        const int n4 = (int)(ACTN / 4);  // 1572864
        const int stride = 768 * 256;
        for (int i = id * 256 + threadIdx.x; i < n4; i += stride) {
            const float4 v = ((const float4*)x)[i];
            bf16x4 o;
            o[0] = (bf16_t)v.x; o[1] = (bf16_t)v.y;
            o[2] = (bf16_t)v.z; o[3] = (bf16_t)v.w;
            ((bf16x4*)xb)[i] = o;
        }
        return;
    }
    id -= 768;
    const int tx = threadIdx.x & 31, ty0 = threadIdx.x >> 5;
    if (id < 2304) {                     // qkvr permuted transpose
        const int n0 = (id % 96) * 32, k0 = (id / 96) * 32;
        const int which = n0 / 768, hd0 = n0 % 768;
#pragma unroll
        for (int i = 0; i < 4; i++) {
            int ty = ty0 + 8 * i;
            t[ty][tx] = w_qkvr[(size_t)(k0 + ty) * 3072 + (hd0 + tx) * 4 + which];
        }
        __syncthreads();
#pragma unroll
        for (int i = 0; i < 4; i++) {
            int ty = ty0 + 8 * i;
            wqkvrT[(size_t)(n0 + ty) * 768 + k0 + tx] = (bf16_t)t[tx][ty];
        }
        return;
    }
    id -= 2304;
    if (id < 576) {                      // w_proj [768][768]
        tile_transpose(w_proj, wprojT, 768, 768, (id % 24) * 32, (id / 24) * 32, t, tx, ty0);
        return;
    }
    id -= 576;
    if (id < 2304) {                     // w_ff1 [768][3072]
        tile_transpose(w_ff1, wff1T, 768, 3072, (id % 96) * 32, (id / 96) * 32, t, tx, ty0);
        return;
    }
    id -= 2304;
    {                                    // w_ff2 [3072][768]
        tile_transpose(w_ff2, wff2T, 3072, 768, (id % 24) * 32, (id / 24) * 32, t, tx, ty0);
    }
}

// ---------------------------------------------------------------- GEMM (bf16 MFMA)
// R12 engine: 256(M)x128(N) tile, BK=64, 8 waves 4x2, triple-buffered LDS,
// single barrier + single counted vmcnt per K-tile.

enum { EPI_QKVR = 0, EPI_PROJ = 1, EPI_GELU = 2, EPI_FF2 = 3 };

#define VMW6 asm volatile("s_waitcnt vmcnt(6)" ::: "memory")
#define VMW0 asm volatile("s_waitcnt vmcnt(0)" ::: "memory")
#define VMNONE do {} while (0)

#define RD8(KC, LB) do { \
    _Pragma("unroll") for (int u = 0; u < 4; u++) { \
        af[u]  = *reinterpret_cast<const bf16x8*>((LB) + aoff[KC][u]); \
        bfr[u] = *reinterpret_cast<const bf16x8*>((LB) + boff[KC][u]); \
    } \
} while (0)

#define MM16() do { \
    __builtin_amdgcn_s_setprio(1); \
    _Pragma("unroll") for (int tr = 0; tr < 4; tr++) \
        _Pragma("unroll") for (int tc = 0; tc < 4; tc++) \
            acc[tr][tc] = __builtin_amdgcn_mfma_f32_16x16x32_bf16( \
                af[tr], bfr[tc], acc[tr][tc], 0, 0, 0); \
    __builtin_amdgcn_s_setprio(0); \
} while (0)

#define STAGE6(DB) do { \
    bf16_t* db_ = lds + (DB) * 24576; \
    _Pragma("unroll") for (int i2 = 0; i2 < 4; i2++) { load16_lds(pa[i2], db_ + lA[i2]); pa[i2] += 64; } \
    _Pragma("unroll") for (int i2 = 0; i2 < 2; i2++) { load16_lds(pb[i2], db_ + lB[i2]); pb[i2] += 64; } \
} while (0)

#define TILE1(BUF, DOSTAGE, GATE, DOBAR) do { \
    const char* lb_ = (const char*)lds + (BUF) * 49152; \
    bf16x8 af[4], bfr[4]; \
    RD8(0, lb_); \
    if (DOSTAGE) STAGE6(((BUF) + 2) % 3); \
    MM16(); \
    RD8(1, lb_); \
    MM16(); \
    GATE; \
    if (DOBAR) { __builtin_amdgcn_sched_barrier(0); __builtin_amdgcn_s_barrier(); } \
} while (0)

template <int EPI, int KSTRIDE, int NKT, int NBX, int SPLITS>
__global__ __launch_bounds__(512, 2) void gemmsb_kernel(
    const bf16_t* __restrict__ A,    // [M,KSTRIDE]
    const bf16_t* __restrict__ BT,   // [N,KSTRIDE]
    const float* __restrict__ bias,  // [N] (EPI_QKVR: original qkvr order)
    bf16_t* __restrict__ qo, bf16_t* __restrict__ ko,
    bf16_t* __restrict__ vTo, bf16_t* __restrict__ ro,   // EPI_QKVR outputs
    const float* __restrict__ resid,                     // EPI_PROJ / EPI_FF2 residual
    float* __restrict__ outf,                            // EPI_PROJ / EPI_FF2 fp32 out
    bf16_t* __restrict__ outb,                           // EPI_GELU bf16 out
    float* __restrict__ pbase)                           // split-K partials base
{
    __shared__ __align__(16) bf16_t lds[3 * 24576];  // 144 KiB

    const int tid  = threadIdx.x;
    const int wave = tid >> 6, lane = tid & 63;
    const int quad = lane >> 4, col16 = lane & 15;
    const int wrow = (wave >> 1) * 64, wcol = (wave & 1) * 64;  // 4(M) x 2(N)

    // bijective XCD swizzle (gridDim.x % 8 == 0 for all launches)
    const int cpx  = gridDim.x >> 3;
    const int id   = blockIdx.x;
    int wgid = (id & 7) * cpx + (id >> 3);
    int split = 0;
    if (SPLITS > 1) {
        constexpr int bps = 32 * NBX;  // blocks per split (M=8192 -> 32 rows)
        split = wgid / bps;
        wgid -= split * bps;
    }
    const int bx = wgid % NBX, by = wgid / NBX;
    const int m0 = by * 256, n0 = bx * 128;
    const bf16_t* Ab = A  + (size_t)split * (NKT * 64);
    const bf16_t* Bb = BT + (size_t)split * (NKT * 64);

    // -------- precomputed LDS read byte-offsets
    int aoff[2][4], boff[2][4];
#pragma unroll
    for (int kc = 0; kc < 2; kc++) {
#pragma unroll
        for (int u = 0; u < 4; u++) {
            const int R = wrow + u * 16 + col16;
            aoff[kc][u] = R * 128 + (((kc * 4 + quad) ^ (R & 7)) * 16);
            const int S = wcol + u * 16 + col16;
            boff[kc][u] = 32768 + S * 128 + (((kc * 4 + quad) ^ (S & 7)) * 16);
        }
    }

    // -------- staging maps (source pre-swizzled, LDS dst linear)
    const bf16_t* pa[4]; const bf16_t* pb[2];
    int lA[4], lB[2];
#pragma unroll
    for (int i = 0; i < 4; i++) {
        const int u = tid + 512 * i;
        const int r = u >> 3, j = (u & 7) ^ (r & 7);
        pa[i] = Ab + (size_t)(m0 + r) * KSTRIDE + j * 8;
        lA[i] = u * 8;
    }
#pragma unroll
    for (int i = 0; i < 2; i++) {
        const int u = tid + 512 * i;
        const int r = u >> 3, j = (u & 7) ^ (r & 7);
        pb[i] = Bb + (size_t)(n0 + r) * KSTRIDE + j * 8;
        lB[i] = 16384 + u * 8;
    }

    f32x4 acc[4][4] = {};

    STAGE6(0); STAGE6(1);
    VMW6; __builtin_amdgcn_s_barrier();

#pragma unroll 1
    for (int tg = 0; tg < NKT / 3 - 1; ++tg) {
        TILE1(0, 1, VMW6, 1);
        TILE1(1, 1, VMW6, 1);
        TILE1(2, 1, VMW6, 1);
    }
    TILE1(0, 1, VMW6, 1);
    TILE1(1, 0, VMW0, 1);
    TILE1(2, 0, VMNONE, 0);

    // ---------------- epilogues
    if (EPI == EPI_QKVR) {
        const int whichb = bx / 6;
        if (whichb == 2) {
#pragma unroll
            for (int tr = 0; tr < 4; tr++) {
#pragma unroll
                for (int tc = 0; tc < 4; tc++) {
                    const int hd   = (bx % 6) * 128 + wcol + tc * 16 + col16;
                    const int head = hd / DHEAD, dd = hd % DHEAD;
                    const float bv = bias[hd * 4 + 2];
                    const int row0 = m0 + wrow + tr * 16 + quad * 4;
                    const int b = row0 >> 10, nn0 = row0 & 1023;
                    bf16x4 w;
#pragma unroll
                    for (int rg = 0; rg < 4; rg++) w[rg] = (bf16_t)(acc[tr][tc][rg] + bv);
                    *reinterpret_cast<bf16x4*>(
                        vTo + ((size_t)(b * HEADS + head) * DHEAD + dd) * SEQ + nn0) = w;
                }
            }
        } else {
            bf16_t* dst = (whichb == 0) ? qo : (whichb == 1) ? ko : ro;
#pragma unroll
            for (int tr = 0; tr < 4; tr++) {
#pragma unroll
                for (int tc = 0; tc < 4; tc++) {
                    const int hd   = (bx % 6) * 128 + wcol + tc * 16 + col16;
                    const int head = hd / DHEAD, dd = hd % DHEAD;
                    const float bv = bias[hd * 4 + whichb];
#pragma unroll
                    for (int rg = 0; rg < 4; rg++) {
                        const int row = m0 + wrow + tr * 16 + quad * 4 + rg;
                        const int b = row >> 10, nn = row & 1023;
                        dst[((size_t)(b * HEADS + head) * SEQ + nn) * DHEAD + dd] =
                            (bf16_t)(acc[tr][tc][rg] + bv);
                    }
                }
            }
        }
    } else {
#pragma unroll
        for (int tr = 0; tr < 4; tr++) {
#pragma unroll
            for (int tc = 0; tc < 4; tc++) {
#pragma unroll
                for (int rg = 0; rg < 4; rg++) {
                    const int row  = m0 + wrow + tr * 16 + quad * 4 + rg;
                    const int colg = n0 + wcol + tc * 16 + col16;
                    const float a = acc[tr][tc][rg];
                    if (EPI == EPI_GELU) {
                        const float v = a + bias[colg];
                        const float z = 1.5957691216057308f * v * (1.0f + 0.044715f * v * v);
                        const float g = v / (1.0f + __expf(-z));
                        outb[(size_t)row * 3072 + colg] = (bf16_t)g;
                    } else if (SPLITS > 1 && split > 0) {
                        pbase[(size_t)(split - 1) * ACTN + (size_t)row * EMB + colg] = a;
                    } else {
                        outf[(size_t)row * EMB + colg] =
                            a + bias[colg] + resid[(size_t)row * EMB + colg];
                    }
                }
            }
        }
    }
}

// ---------------------------------------------------------------- attention
// (unchanged)

__global__ __launch_bounds__(256) void attn_kernel(
    const bf16_t* __restrict__ q, const bf16_t* __restrict__ k,
    const bf16_t* __restrict__ vT, const bf16_t* __restrict__ r,
    bf16_t* __restrict__ attn_out)
{
    __shared__ __align__(16) bf16_t Ks[64 * 96];
    __shared__ __align__(16) bf16_t Vs[96 * 64];
    __shared__ __align__(16) bf16_t P[4][16 * 72];

    const int tid = threadIdx.x, wave = tid >> 6, lane = tid & 63;
    const int quad = lane >> 4, col = lane & 15;
    const int bh = blockIdx.x & 63, qb = blockIdx.x >> 6;
    const int n0 = qb * 64 + wave * 16;
    const bf16_t* qp = q  + (size_t)bh * SEQ * DHEAD;
    const bf16_t* kb = k  + (size_t)bh * SEQ * DHEAD;
    const bf16_t* vb = vT + (size_t)bh * DHEAD * SEQ;
    bf16_t* Pw = P[wave];

    bf16x8 qf[3];
#pragma unroll
    for (int ks = 0; ks < 3; ks++)
        qf[ks] = *reinterpret_cast<const bf16x8*>(qp + (size_t)(n0 + col) * DHEAD + ks * 32 + quad * 8);

    const int u0 = tid, u1 = tid + 256, u2 = tid + 512;
    const int vf0 = u0 >> 3, vp0 = (u0 & 7) ^ (vf0 & 7);
    const int vf1 = u1 >> 3, vp1 = (u1 & 7) ^ (vf1 & 7);
    const int vf2 = u2 >> 3, vp2 = (u2 & 7) ^ (vf2 & 7);

    f32x4 O[6] = {};
    float lsum = 0.f;

    for (int ch = 0; ch < SEQ / 64; ch++) {
        const int kc0 = ch * 64;
        __syncthreads();
        const bf16_t* ksrc = kb + (size_t)kc0 * DHEAD;
        load16_lds(ksrc + u0 * 8, Ks + u0 * 8);
        load16_lds(ksrc + u1 * 8, Ks + u1 * 8);
        load16_lds(ksrc + u2 * 8, Ks + u2 * 8);
        load16_lds(vb + (size_t)vf0 * SEQ + kc0 + vp0 * 8, Vs + u0 * 8);
        load16_lds(vb + (size_t)vf1 * SEQ + kc0 + vp1 * 8, Vs + u1 * 8);
        load16_lds(vb + (size_t)vf2 * SEQ + kc0 + vp2 * 8, Vs + u2 * 8);
        __syncthreads();

        f32x4 s[4] = {};
#pragma unroll
        for (int ks = 0; ks < 3; ks++) {
#pragma unroll
            for (int h = 0; h < 4; h++) {
                bf16x8 kf = *reinterpret_cast<const bf16x8*>(Ks + (h * 16 + col) * DHEAD + ks * 32 + quad * 8);
                s[h] = __builtin_amdgcn_mfma_f32_16x16x32_bf16(kf, qf[ks], s[h], 0, 0, 0);
            }
        }
#pragma unroll
        for (int h = 0; h < 4; h++) {
            bf16x4 w;
#pragma unroll
            for (int rg = 0; rg < 4; rg++) {
                const float e = __expf(s[h][rg]);
                lsum += e;
                w[rg] = (bf16_t)e;
            }
            *reinterpret_cast<bf16x4*>(Pw + col * 72 + h * 16 + quad * 4) = w;
        }
        bf16x8 af0 = *reinterpret_cast<const bf16x8*>(Pw + col * 72 + quad * 8);
        bf16x8 af1 = *reinterpret_cast<const bf16x8*>(Pw + col * 72 + 32 + quad * 8);
#pragma unroll
        for (int tc = 0; tc < 6; tc++) {
            const int feat = tc * 16 + col;
            bf16x8 bv0 = *reinterpret_cast<const bf16x8*>(Vs + feat * 64 + ((quad)     ^ (col & 7)) * 8);
            bf16x8 bv1 = *reinterpret_cast<const bf16x8*>(Vs + feat * 64 + ((4 + quad) ^ (col & 7)) * 8);
            O[tc] = __builtin_amdgcn_mfma_f32_16x16x32_bf16(af0, bv0, O[tc], 0, 0, 0);
            O[tc] = __builtin_amdgcn_mfma_f32_16x16x32_bf16(af1, bv1, O[tc], 0, 0, 0);
        }
    }

    lsum += __shfl_xor(lsum, 16);
    lsum += __shfl_xor(lsum, 32);

    const float inv_sqrt_emb = 0.036084391824351615f;
    const int b = bh >> 3, h = bh & 7;
#pragma unroll
    for (int rg = 0; rg < 4; rg++) {
        const int nrow = quad * 4 + rg;
        const float lr = __shfl(lsum, nrow);
        const float scale = inv_sqrt_emb / lr;
        const int n = n0 + nrow;
#pragma unroll
        for (int tc = 0; tc < 6; tc++) {
            const int feat = tc * 16 + col;
            const float rv = (float)r[((size_t)bh * SEQ + n) * DHEAD + feat];
            attn_out[((size_t)(b * SEQ + n)) * EMB + h * DHEAD + feat] = (bf16_t)(O[tc][rg] * scale * rv);
        }
    }
}

// ---------------------------------------------------------------- LayerNorm (row=768)
// vectorized float4; in2/in3/in4 optional partial-sum inputs (FF2 split-K).

__global__ __launch_bounds__(256) void ln_kernel(
    const float* __restrict__ in, const float* __restrict__ in2,
    const float* __restrict__ in3, const float* __restrict__ in4,
    const float* __restrict__ g, const float* __restrict__ b,
    float* __restrict__ y, bf16_t* __restrict__ yb)
{
    const int row = blockIdx.x * 4 + (threadIdx.x >> 6);
    const int lane = threadIdx.x & 63;
    const float4* rp  = (const float4*)(in + (size_t)row * EMB);
    const float4* rp2 = in2 ? (const float4*)(in2 + (size_t)row * EMB) : nullptr;
    const float4* rp3 = in3 ? (const float4*)(in3 + (size_t)row * EMB) : nullptr;
    const float4* rp4 = in4 ? (const float4*)(in4 + (size_t)row * EMB) : nullptr;
    float4 v[3];
    float sum = 0.f;
#pragma unroll
    for (int i = 0; i < 3; i++) {
        float4 t = rp[lane + i * 64];
        if (in2) { float4 a = rp2[lane + i * 64]; t.x += a.x; t.y += a.y; t.z += a.z; t.w += a.w; }
        if (in3) { float4 a = rp3[lane + i * 64]; t.x += a.x; t.y += a.y; t.z += a.z; t.w += a.w; }
        if (in4) { float4 a = rp4[lane + i * 64]; t.x += a.x; t.y += a.y; t.z += a.z; t.w += a.w; }
        v[i] = t;
        sum += t.x + t.y + t.z + t.w;
    }
#pragma unroll
    for (int off = 32; off; off >>= 1) sum += __shfl_xor(sum, off);
    const float mean = sum * (1.0f / 768.0f);
    float s2 = 0.f;
#pragma unroll
    for (int i = 0; i < 3; i++) {
        float dx = v[i].x - mean, dy = v[i].y - mean, dz = v[i].z - mean, dw = v[i].w - mean;
        s2 += dx * dx + dy * dy + dz * dz + dw * dw;
    }
#pragma unroll
    for (int off = 32; off; off >>= 1) s2 += __shfl_xor(s2, off);
    const float inv = rsqrtf(s2 * (1.0f / 768.0f) + 1e-5f);
    const float4* g4 = (const float4*)g;
    const float4* b4 = (const float4*)b;
#pragma unroll
    for (int i = 0; i < 3; i++) {
        const int c4 = lane + i * 64;
        const float4 gg = g4[c4], bb = b4[c4];
        float4 o;
        o.x = (v[i].x - mean) * inv * gg.x + bb.x;
        o.y = (v[i].y - mean) * inv * gg.y + bb.y;
        o.z = (v[i].z - mean) * inv * gg.z + bb.z;
        o.w = (v[i].w - mean) * inv * gg.w + bb.w;
        ((float4*)(y + (size_t)row * EMB))[c4] = o;
        if (yb) {
            bf16x4 ob;
            ob[0] = (bf16_t)o.x; ob[1] = (bf16_t)o.y; ob[2] = (bf16_t)o.z; ob[3] = (bf16_t)o.w;
            *reinterpret_cast<bf16x4*>(yb + (size_t)row * EMB + c4 * 4) = ob;
        }
    }
}

// ---------------------------------------------------------------- launch

extern "C" void kernel_launch(void* const* d_in, const int* in_sizes, int n_in,
                              void* d_out, int out_size, void* d_ws, size_t ws_size,
                              hipStream_t stream)
{
    const float* x      = (const float*)d_in[0];
    const float* w_qkvr = (const float*)d_in[1];
    const float* b_qkvr = (const float*)d_in[2];
    const float* w_proj = (const float*)d_in[3];
    const float* b_proj = (const float*)d_in[4];
    const float* ln1_g  = (const float*)d_in[5];
    const float* ln1_b  = (const float*)d_in[6];
    const float* w_ff1  = (const float*)d_in[7];
    const float* b_ff1  = (const float*)d_in[8];
    const float* w_ff2  = (const float*)d_in[9];
    const float* b_ff2  = (const float*)d_in[10];
    const float* ln2_g  = (const float*)d_in[11];
    const float* ln2_b  = (const float*)d_in[12];
    float* out = (float*)d_out;

    char* ws = (char*)d_ws;
    size_t off = 0;
    auto alloc = [&](size_t bytes) {
        char* p = ws + off;
        off += (bytes + 255) & ~(size_t)255;
        return (void*)p;
    };
    // persistent-through-FF2 buffers first; then the region that is DEAD by
    // FF2 time (xb..attn_o, 6 x ACT bf16 = 75.5MB) which FF2's fp32 partials
    // (3 x ACT floats = 75.5MB) overlay exactly.
    bf16_t* wqkvrT  = (bf16_t*)alloc((size_t)3072 * 768 * 2);
    bf16_t* wprojT  = (bf16_t*)alloc((size_t)768 * 768 * 2);
    bf16_t* wff1T   = (bf16_t*)alloc((size_t)3072 * 768 * 2);
    bf16_t* wff2T   = (bf16_t*)alloc((size_t)768 * 3072 * 2);
    float*  x1f     = (float*)alloc(ACTN * 4);
    bf16_t* x1b     = (bf16_t*)alloc(ACTN * 2);
    bf16_t* ff1     = (bf16_t*)alloc((size_t)ROWS * 3072 * 2);
    bf16_t* xb      = (bf16_t*)alloc(ACTN * 2);   // dead region starts here
    bf16_t* qbuf    = (bf16_t*)alloc(ACTN * 2);
    bf16_t* kbuf    = (bf16_t*)alloc(ACTN * 2);
    bf16_t* vTbuf   = (bf16_t*)alloc(ACTN * 2);
    bf16_t* rbuf    = (bf16_t*)alloc(ACTN * 2);
    bf16_t* attn_o  = (bf16_t*)alloc(ACTN * 2);
    float*  res     = out;               // d_out doubles as fp32 residual scratch
    float*  pbase   = (float*)xb;        // FF2 partials 1..3 (xb..attn_o dead)

    // prep: cvt + all 4 weight transposes, one dispatch
    prep_kernel<<<8256, 256, 0, stream>>>(x, xb, w_qkvr, wqkvrT, w_proj, wprojT,
                                          w_ff1, wff1T, w_ff2, wff2T);

    // QKVR: M=8192, N=3072 -> 32 x 24 = 768 blocks (3 clean CU-rounds)
    gemmsb_kernel<EPI_QKVR, 768, 12, 24, 1><<<768, 512, 0, stream>>>(
        xb, wqkvrT, b_qkvr, qbuf, kbuf, vTbuf, rbuf, nullptr, nullptr, nullptr, nullptr);

    attn_kernel<<<dim3(SEQ / 64 * BATCH * HEADS), 256, 0, stream>>>(qbuf, kbuf, vTbuf, rbuf, attn_o);

    // PROJ: M=8192, N=768 -> 32 x 6 = 192 blocks
    gemmsb_kernel<EPI_PROJ, 768, 12, 6, 1><<<192, 512, 0, stream>>>(
        attn_o, wprojT, b_proj, nullptr, nullptr, nullptr, nullptr, x, res, nullptr, nullptr);
    ln_kernel<<<2048, 256, 0, stream>>>(res, nullptr, nullptr, nullptr, ln1_g, ln1_b, x1f, x1b);

    // FF1+GELU: M=8192, N=3072
    gemmsb_kernel<EPI_GELU, 768, 12, 24, 1><<<768, 512, 0, stream>>>(
        x1b, wff1T, b_ff1, nullptr, nullptr, nullptr, nullptr, nullptr, nullptr, ff1, nullptr);

    // FF2: M=8192, N=768, K=3072, split-K x4 -> 768 blocks (3 clean rounds),
    // 12 K-tiles each. split 0 adds bias+residual; splits 1-3 raw partials.
    gemmsb_kernel<EPI_FF2, 3072, 12, 6, 4><<<768, 512, 0, stream>>>(
        ff1, wff2T, b_ff2, nullptr, nullptr, nullptr, nullptr, x1f, res, nullptr, pbase);
    ln_kernel<<<2048, 256, 0, stream>>>(res, pbase, pbase + ACTN, pbase + 2 * ACTN,
                                        ln2_g, ln2_b, out, nullptr);

    (void)in_sizes; (void)n_in; (void)out_size; (void)ws_size;
}

// Round 7
// 358.107 us; speedup vs baseline: 1.1604x; 1.1604x over previous
//
#include <hip/hip_runtime.h>
#include <math.h>

// EncoderBlock: B=8, N=1024, EMB=768, HEADS=8, DHEAD=96
// R15 = R14 with FF2 split-K reverted (R14 post-mortem: split-K x4 added
//       150 MB of partial-write + LN2-read HBM traffic -> FF2 63 -> 96 us.
//       Non-split FF2 at 192 blocks is L2-friendly and was never the
//       bottleneck). Kept from R14: fused prep (1 dispatch), vectorized LN.
//       GEMM engine: R12 single-barrier triple-buffer (structural plateau,
//       ~16 cy/MFMA across 5 schedule variants — do not re-roll).

typedef __bf16 bf16_t;
typedef __bf16 bf16x4 __attribute__((ext_vector_type(4)));
typedef __bf16 bf16x8 __attribute__((ext_vector_type(8)));
typedef float f32x4 __attribute__((ext_vector_type(4)));

#define EMB   768
#define HEADS 8
#define DHEAD 96
#define BATCH 8
#define SEQ   1024
#define ROWS  (BATCH * SEQ)   // 8192
#define ACTN  ((size_t)ROWS * EMB)  // 6291456

__device__ __forceinline__ void load16_lds(const bf16_t* g, bf16_t* l) {
    __builtin_amdgcn_global_load_lds(
        (__attribute__((address_space(1))) unsigned int*)g,
        (__attribute__((address_space(3))) unsigned int*)l,
        16, 0, 0);
}

// ---------------------------------------------------------------- fused prep
// Sections (1D grid, 256 thr):
//   [0,768)        : x fp32 -> xb bf16 (float4/bf16x4)
//   [768,3072)     : qkvr permuted transpose  (96 x 24 tiles)
//   [3072,3648)    : w_proj transpose         (24 x 24)
//   [3648,5952)    : w_ff1 transpose          (96 x 24)
//   [5952,8256)    : w_ff2 transpose          (24 x 96)

__device__ __forceinline__ void tile_transpose(
    const float* __restrict__ in, bf16_t* __restrict__ out,
    int K, int N, int n0, int k0, float (*t)[33], int tx, int ty0)
{
#pragma unroll
    for (int i = 0; i < 4; i++) {
        int ty = ty0 + 8 * i;
        t[ty][tx] = in[(size_t)(k0 + ty) * N + n0 + tx];
    }
    __syncthreads();
#pragma unroll
    for (int i = 0; i < 4; i++) {
        int ty = ty0 + 8 * i;
        out[(size_t)(n0 + ty) * K + k0 + tx] = (bf16_t)t[tx][ty];
    }
}

__global__ __launch_bounds__(256) void prep_kernel(
    const float* __restrict__ x, bf16_t* __restrict__ xb,
    const float* __restrict__ w_qkvr, bf16_t* __restrict__ wqkvrT,
    const float* __restrict__ w_proj, bf16_t* __restrict__ wprojT,
    const float* __restrict__ w_ff1, bf16_t* __restrict__ wff1T,
    const float* __restrict__ w_ff2, bf16_t* __restrict__ wff2T)
{
    __shared__ float t[32][33];
    int id = blockIdx.x;
    if (id < 768) {                      // cvt x -> xb
        const int n4 = (int)(ACTN / 4);  // 1572864
        const int stride = 768 * 256;
        for (int i = id * 256 + threadIdx.x; i < n4; i += stride) {
            const float4 v = ((const float4*)x)[i];
            bf16x4 o;
            o[0] = (bf16_t)v.x; o[1] = (bf16_t)v.y;
            o[2] = (bf16_t)v.z; o[3] = (bf16_t)v.w;
            ((bf16x4*)xb)[i] = o;
        }
        return;
    }
    id -= 768;
    const int tx = threadIdx.x & 31, ty0 = threadIdx.x >> 5;
    if (id < 2304) {                     // qkvr permuted transpose
        const int n0 = (id % 96) * 32, k0 = (id / 96) * 32;
        const int which = n0 / 768, hd0 = n0 % 768;
#pragma unroll
        for (int i = 0; i < 4; i++) {
            int ty = ty0 + 8 * i;
            t[ty][tx] = w_qkvr[(size_t)(k0 + ty) * 3072 + (hd0 + tx) * 4 + which];
        }
        __syncthreads();
#pragma unroll
        for (int i = 0; i < 4; i++) {
            int ty = ty0 + 8 * i;
            wqkvrT[(size_t)(n0 + ty) * 768 + k0 + tx] = (bf16_t)t[tx][ty];
        }
        return;
    }
    id -= 2304;
    if (id < 576) {                      // w_proj [768][768]
        tile_transpose(w_proj, wprojT, 768, 768, (id % 24) * 32, (id / 24) * 32, t, tx, ty0);
        return;
    }
    id -= 576;
    if (id < 2304) {                     // w_ff1 [768][3072]
        tile_transpose(w_ff1, wff1T, 768, 3072, (id % 96) * 32, (id / 96) * 32, t, tx, ty0);
        return;
    }
    id -= 2304;
    {                                    // w_ff2 [3072][768]
        tile_transpose(w_ff2, wff2T, 3072, 768, (id % 24) * 32, (id / 24) * 32, t, tx, ty0);
    }
}

// ---------------------------------------------------------------- GEMM (bf16 MFMA)
// R12 engine: 256(M)x128(N) tile, BK=64, 8 waves 4x2, triple-buffered LDS,
// single barrier + single counted vmcnt per K-tile.

enum { EPI_QKVR = 0, EPI_PROJ = 1, EPI_GELU = 2, EPI_FF2 = 3 };

#define VMW6 asm volatile("s_waitcnt vmcnt(6)" ::: "memory")
#define VMW0 asm volatile("s_waitcnt vmcnt(0)" ::: "memory")
#define VMNONE do {} while (0)

#define RD8(KC, LB) do { \
    _Pragma("unroll") for (int u = 0; u < 4; u++) { \
        af[u]  = *reinterpret_cast<const bf16x8*>((LB) + aoff[KC][u]); \
        bfr[u] = *reinterpret_cast<const bf16x8*>((LB) + boff[KC][u]); \
    } \
} while (0)

#define MM16() do { \
    __builtin_amdgcn_s_setprio(1); \
    _Pragma("unroll") for (int tr = 0; tr < 4; tr++) \
        _Pragma("unroll") for (int tc = 0; tc < 4; tc++) \
            acc[tr][tc] = __builtin_amdgcn_mfma_f32_16x16x32_bf16( \
                af[tr], bfr[tc], acc[tr][tc], 0, 0, 0); \
    __builtin_amdgcn_s_setprio(0); \
} while (0)

#define STAGE6(DB) do { \
    bf16_t* db_ = lds + (DB) * 24576; \
    _Pragma("unroll") for (int i2 = 0; i2 < 4; i2++) { load16_lds(pa[i2], db_ + lA[i2]); pa[i2] += 64; } \
    _Pragma("unroll") for (int i2 = 0; i2 < 2; i2++) { load16_lds(pb[i2], db_ + lB[i2]); pb[i2] += 64; } \
} while (0)

#define TILE1(BUF, DOSTAGE, GATE, DOBAR) do { \
    const char* lb_ = (const char*)lds + (BUF) * 49152; \
    bf16x8 af[4], bfr[4]; \
    RD8(0, lb_); \
    if (DOSTAGE) STAGE6(((BUF) + 2) % 3); \
    MM16(); \
    RD8(1, lb_); \
    MM16(); \
    GATE; \
    if (DOBAR) { __builtin_amdgcn_sched_barrier(0); __builtin_amdgcn_s_barrier(); } \
} while (0)

template <int EPI, int KSTRIDE, int NKT, int NBX>
__global__ __launch_bounds__(512, 2) void gemmsb_kernel(
    const bf16_t* __restrict__ A,    // [M,KSTRIDE]
    const bf16_t* __restrict__ BT,   // [N,KSTRIDE]
    const float* __restrict__ bias,  // [N] (EPI_QKVR: original qkvr order)
    bf16_t* __restrict__ qo, bf16_t* __restrict__ ko,
    bf16_t* __restrict__ vTo, bf16_t* __restrict__ ro,   // EPI_QKVR outputs
    const float* __restrict__ resid,                     // EPI_PROJ / EPI_FF2 residual
    float* __restrict__ outf,                            // EPI_PROJ / EPI_FF2 fp32 out
    bf16_t* __restrict__ outb)                           // EPI_GELU bf16 out
{
    __shared__ __align__(16) bf16_t lds[3 * 24576];  // 144 KiB

    const int tid  = threadIdx.x;
    const int wave = tid >> 6, lane = tid & 63;
    const int quad = lane >> 4, col16 = lane & 15;
    const int wrow = (wave >> 1) * 64, wcol = (wave & 1) * 64;  // 4(M) x 2(N)

    // bijective XCD swizzle (gridDim.x % 8 == 0 for all launches)
    const int cpx  = gridDim.x >> 3;
    const int id   = blockIdx.x;
    const int wgid = (id & 7) * cpx + (id >> 3);
    const int bx = wgid % NBX, by = wgid / NBX;
    const int m0 = by * 256, n0 = bx * 128;

    // -------- precomputed LDS read byte-offsets
    int aoff[2][4], boff[2][4];
#pragma unroll
    for (int kc = 0; kc < 2; kc++) {
#pragma unroll
        for (int u = 0; u < 4; u++) {
            const int R = wrow + u * 16 + col16;
            aoff[kc][u] = R * 128 + (((kc * 4 + quad) ^ (R & 7)) * 16);
            const int S = wcol + u * 16 + col16;
            boff[kc][u] = 32768 + S * 128 + (((kc * 4 + quad) ^ (S & 7)) * 16);
        }
    }

    // -------- staging maps (source pre-swizzled, LDS dst linear)
    const bf16_t* pa[4]; const bf16_t* pb[2];
    int lA[4], lB[2];
#pragma unroll
    for (int i = 0; i < 4; i++) {
        const int u = tid + 512 * i;
        const int r = u >> 3, j = (u & 7) ^ (r & 7);
        pa[i] = A + (size_t)(m0 + r) * KSTRIDE + j * 8;
        lA[i] = u * 8;
    }
#pragma unroll
    for (int i = 0; i < 2; i++) {
        const int u = tid + 512 * i;
        const int r = u >> 3, j = (u & 7) ^ (r & 7);
        pb[i] = BT + (size_t)(n0 + r) * KSTRIDE + j * 8;
        lB[i] = 16384 + u * 8;
    }

    f32x4 acc[4][4] = {};

    STAGE6(0); STAGE6(1);
    VMW6; __builtin_amdgcn_s_barrier();

#pragma unroll 1
    for (int tg = 0; tg < NKT / 3 - 1; ++tg) {
        TILE1(0, 1, VMW6, 1);
        TILE1(1, 1, VMW6, 1);
        TILE1(2, 1, VMW6, 1);
    }
    TILE1(0, 1, VMW6, 1);
    TILE1(1, 0, VMW0, 1);
    TILE1(2, 0, VMNONE, 0);

    // ---------------- epilogues
    if (EPI == EPI_QKVR) {
        const int whichb = bx / 6;
        if (whichb == 2) {
#pragma unroll
            for (int tr = 0; tr < 4; tr++) {
#pragma unroll
                for (int tc = 0; tc < 4; tc++) {
                    const int hd   = (bx % 6) * 128 + wcol + tc * 16 + col16;
                    const int head = hd / DHEAD, dd = hd % DHEAD;
                    const float bv = bias[hd * 4 + 2];
                    const int row0 = m0 + wrow + tr * 16 + quad * 4;
                    const int b = row0 >> 10, nn0 = row0 & 1023;
                    bf16x4 w;
#pragma unroll
                    for (int rg = 0; rg < 4; rg++) w[rg] = (bf16_t)(acc[tr][tc][rg] + bv);
                    *reinterpret_cast<bf16x4*>(
                        vTo + ((size_t)(b * HEADS + head) * DHEAD + dd) * SEQ + nn0) = w;
                }
            }
        } else {
            bf16_t* dst = (whichb == 0) ? qo : (whichb == 1) ? ko : ro;
#pragma unroll
            for (int tr = 0; tr < 4; tr++) {
#pragma unroll
                for (int tc = 0; tc < 4; tc++) {
                    const int hd   = (bx % 6) * 128 + wcol + tc * 16 + col16;
                    const int head = hd / DHEAD, dd = hd % DHEAD;
                    const float bv = bias[hd * 4 + whichb];
#pragma unroll
                    for (int rg = 0; rg < 4; rg++) {
                        const int row = m0 + wrow + tr * 16 + quad * 4 + rg;
                        const int b = row >> 10, nn = row & 1023;
                        dst[((size_t)(b * HEADS + head) * SEQ + nn) * DHEAD + dd] =
                            (bf16_t)(acc[tr][tc][rg] + bv);
                    }
                }
            }
        }
    } else {
#pragma unroll
        for (int tr = 0; tr < 4; tr++) {
#pragma unroll
            for (int tc = 0; tc < 4; tc++) {
#pragma unroll
                for (int rg = 0; rg < 4; rg++) {
                    const int row  = m0 + wrow + tr * 16 + quad * 4 + rg;
                    const int colg = n0 + wcol + tc * 16 + col16;
                    float v = acc[tr][tc][rg] + bias[colg];
                    if (EPI == EPI_PROJ || EPI == EPI_FF2) {
                        outf[(size_t)row * EMB + colg] = v + resid[(size_t)row * EMB + colg];
                    } else {  // EPI_GELU: tanh-form gelu via sigmoid (|err|<3e-3 vs erf)
                        const float z = 1.5957691216057308f * v * (1.0f + 0.044715f * v * v);
                        const float g = v / (1.0f + __expf(-z));
                        outb[(size_t)row * 3072 + colg] = (bf16_t)g;
                    }
                }
            }
        }
    }
}

// ---------------------------------------------------------------- attention
// (unchanged)

__global__ __launch_bounds__(256) void attn_kernel(
    const bf16_t* __restrict__ q, const bf16_t* __restrict__ k,
    const bf16_t* __restrict__ vT, const bf16_t* __restrict__ r,
    bf16_t* __restrict__ attn_out)
{
    __shared__ __align__(16) bf16_t Ks[64 * 96];
    __shared__ __align__(16) bf16_t Vs[96 * 64];
    __shared__ __align__(16) bf16_t P[4][16 * 72];

    const int tid = threadIdx.x, wave = tid >> 6, lane = tid & 63;
    const int quad = lane >> 4, col = lane & 15;
    const int bh = blockIdx.x & 63, qb = blockIdx.x >> 6;
    const int n0 = qb * 64 + wave * 16;
    const bf16_t* qp = q  + (size_t)bh * SEQ * DHEAD;
    const bf16_t* kb = k  + (size_t)bh * SEQ * DHEAD;
    const bf16_t* vb = vT + (size_t)bh * DHEAD * SEQ;
    bf16_t* Pw = P[wave];

    bf16x8 qf[3];
#pragma unroll
    for (int ks = 0; ks < 3; ks++)
        qf[ks] = *reinterpret_cast<const bf16x8*>(qp + (size_t)(n0 + col) * DHEAD + ks * 32 + quad * 8);

    const int u0 = tid, u1 = tid + 256, u2 = tid + 512;
    const int vf0 = u0 >> 3, vp0 = (u0 & 7) ^ (vf0 & 7);
    const int vf1 = u1 >> 3, vp1 = (u1 & 7) ^ (vf1 & 7);
    const int vf2 = u2 >> 3, vp2 = (u2 & 7) ^ (vf2 & 7);

    f32x4 O[6] = {};
    float lsum = 0.f;

    for (int ch = 0; ch < SEQ / 64; ch++) {
        const int kc0 = ch * 64;
        __syncthreads();
        const bf16_t* ksrc = kb + (size_t)kc0 * DHEAD;
        load16_lds(ksrc + u0 * 8, Ks + u0 * 8);
        load16_lds(ksrc + u1 * 8, Ks + u1 * 8);
        load16_lds(ksrc + u2 * 8, Ks + u2 * 8);
        load16_lds(vb + (size_t)vf0 * SEQ + kc0 + vp0 * 8, Vs + u0 * 8);
        load16_lds(vb + (size_t)vf1 * SEQ + kc0 + vp1 * 8, Vs + u1 * 8);
        load16_lds(vb + (size_t)vf2 * SEQ + kc0 + vp2 * 8, Vs + u2 * 8);
        __syncthreads();

        f32x4 s[4] = {};
#pragma unroll
        for (int ks = 0; ks < 3; ks++) {
#pragma unroll
            for (int h = 0; h < 4; h++) {
                bf16x8 kf = *reinterpret_cast<const bf16x8*>(Ks + (h * 16 + col) * DHEAD + ks * 32 + quad * 8);
                s[h] = __builtin_amdgcn_mfma_f32_16x16x32_bf16(kf, qf[ks], s[h], 0, 0, 0);
            }
        }
#pragma unroll
        for (int h = 0; h < 4; h++) {
            bf16x4 w;
#pragma unroll
            for (int rg = 0; rg < 4; rg++) {
                const float e = __expf(s[h][rg]);
                lsum += e;
                w[rg] = (bf16_t)e;
            }
            *reinterpret_cast<bf16x4*>(Pw + col * 72 + h * 16 + quad * 4) = w;
        }
        bf16x8 af0 = *reinterpret_cast<const bf16x8*>(Pw + col * 72 + quad * 8);
        bf16x8 af1 = *reinterpret_cast<const bf16x8*>(Pw + col * 72 + 32 + quad * 8);
#pragma unroll
        for (int tc = 0; tc < 6; tc++) {
            const int feat = tc * 16 + col;
            bf16x8 bv0 = *reinterpret_cast<const bf16x8*>(Vs + feat * 64 + ((quad)     ^ (col & 7)) * 8);
            bf16x8 bv1 = *reinterpret_cast<const bf16x8*>(Vs + feat * 64 + ((4 + quad) ^ (col & 7)) * 8);
            O[tc] = __builtin_amdgcn_mfma_f32_16x16x32_bf16(af0, bv0, O[tc], 0, 0, 0);
            O[tc] = __builtin_amdgcn_mfma_f32_16x16x32_bf16(af1, bv1, O[tc], 0, 0, 0);
        }
    }

    lsum += __shfl_xor(lsum, 16);
    lsum += __shfl_xor(lsum, 32);

    const float inv_sqrt_emb = 0.036084391824351615f;
    const int b = bh >> 3, h = bh & 7;
#pragma unroll
    for (int rg = 0; rg < 4; rg++) {
        const int nrow = quad * 4 + rg;
        const float lr = __shfl(lsum, nrow);
        const float scale = inv_sqrt_emb / lr;
        const int n = n0 + nrow;
#pragma unroll
        for (int tc = 0; tc < 6; tc++) {
            const int feat = tc * 16 + col;
            const float rv = (float)r[((size_t)bh * SEQ + n) * DHEAD + feat];
            attn_out[((size_t)(b * SEQ + n)) * EMB + h * DHEAD + feat] = (bf16_t)(O[tc][rg] * scale * rv);
        }
    }
}

// ---------------------------------------------------------------- LayerNorm (row=768)
// vectorized float4 / bf16x4.

__global__ __launch_bounds__(256) void ln_kernel(
    const float* __restrict__ in,
    const float* __restrict__ g, const float* __restrict__ b,
    float* __restrict__ y, bf16_t* __restrict__ yb)
{
    const int row = blockIdx.x * 4 + (threadIdx.x >> 6);
    const int lane = threadIdx.x & 63;
    const float4* rp = (const float4*)(in + (size_t)row * EMB);
    float4 v[3];
    float sum = 0.f;
#pragma unroll
    for (int i = 0; i < 3; i++) {
        float4 t = rp[lane + i * 64];
        v[i] = t;
        sum += t.x + t.y + t.z + t.w;
    }
#pragma unroll
    for (int off = 32; off; off >>= 1) sum += __shfl_xor(sum, off);
    const float mean = sum * (1.0f / 768.0f);
    float s2 = 0.f;
#pragma unroll
    for (int i = 0; i < 3; i++) {
        float dx = v[i].x - mean, dy = v[i].y - mean, dz = v[i].z - mean, dw = v[i].w - mean;
        s2 += dx * dx + dy * dy + dz * dz + dw * dw;
    }
#pragma unroll
    for (int off = 32; off; off >>= 1) s2 += __shfl_xor(s2, off);
    const float inv = rsqrtf(s2 * (1.0f / 768.0f) + 1e-5f);
    const float4* g4 = (const float4*)g;
    const float4* b4 = (const float4*)b;
#pragma unroll
    for (int i = 0; i < 3; i++) {
        const int c4 = lane + i * 64;
        const float4 gg = g4[c4], bb = b4[c4];
        float4 o;
        o.x = (v[i].x - mean) * inv * gg.x + bb.x;
        o.y = (v[i].y - mean) * inv * gg.y + bb.y;
        o.z = (v[i].z - mean) * inv * gg.z + bb.z;
        o.w = (v[i].w - mean) * inv * gg.w + bb.w;
        ((float4*)(y + (size_t)row * EMB))[c4] = o;
        if (yb) {
            bf16x4 ob;
            ob[0] = (bf16_t)o.x; ob[1] = (bf16_t)o.y; ob[2] = (bf16_t)o.z; ob[3] = (bf16_t)o.w;
            *reinterpret_cast<bf16x4*>(yb + (size_t)row * EMB + c4 * 4) = ob;
        }
    }
}

// ---------------------------------------------------------------- launch

extern "C" void kernel_launch(void* const* d_in, const int* in_sizes, int n_in,
                              void* d_out, int out_size, void* d_ws, size_t ws_size,
                              hipStream_t stream)
{
    const float* x      = (const float*)d_in[0];
    const float* w_qkvr = (const float*)d_in[1];
    const float* b_qkvr = (const float*)d_in[2];
    const float* w_proj = (const float*)d_in[3];
    const float* b_proj = (const float*)d_in[4];
    const float* ln1_g  = (const float*)d_in[5];
    const float* ln1_b  = (const float*)d_in[6];
    const float* w_ff1  = (const float*)d_in[7];
    const float* b_ff1  = (const float*)d_in[8];
    const float* w_ff2  = (const float*)d_in[9];
    const float* b_ff2  = (const float*)d_in[10];
    const float* ln2_g  = (const float*)d_in[11];
    const float* ln2_b  = (const float*)d_in[12];
    float* out = (float*)d_out;

    char* ws = (char*)d_ws;
    size_t off = 0;
    auto alloc = [&](size_t bytes) {
        char* p = ws + off;
        off += (bytes + 255) & ~(size_t)255;
        return (void*)p;
    };
    bf16_t* wqkvrT  = (bf16_t*)alloc((size_t)3072 * 768 * 2);
    bf16_t* wprojT  = (bf16_t*)alloc((size_t)768 * 768 * 2);
    bf16_t* wff1T   = (bf16_t*)alloc((size_t)3072 * 768 * 2);
    bf16_t* wff2T   = (bf16_t*)alloc((size_t)768 * 3072 * 2);
    float*  x1f     = (float*)alloc(ACTN * 4);
    bf16_t* x1b     = (bf16_t*)alloc(ACTN * 2);
    bf16_t* ff1     = (bf16_t*)alloc((size_t)ROWS * 3072 * 2);
    bf16_t* xb      = (bf16_t*)alloc(ACTN * 2);
    bf16_t* qbuf    = (bf16_t*)alloc(ACTN * 2);
    bf16_t* kbuf    = (bf16_t*)alloc(ACTN * 2);
    bf16_t* vTbuf   = (bf16_t*)alloc(ACTN * 2);
    bf16_t* rbuf    = (bf16_t*)alloc(ACTN * 2);
    bf16_t* attn_o  = (bf16_t*)alloc(ACTN * 2);
    float*  res     = out;  // d_out doubles as fp32 residual scratch

    // prep: cvt + all 4 weight transposes, one dispatch
    prep_kernel<<<8256, 256, 0, stream>>>(x, xb, w_qkvr, wqkvrT, w_proj, wprojT,
                                          w_ff1, wff1T, w_ff2, wff2T);

    // QKVR: M=8192, N=3072 -> 32 x 24 = 768 blocks (3 clean CU-rounds)
    gemmsb_kernel<EPI_QKVR, 768, 12, 24><<<768, 512, 0, stream>>>(
        xb, wqkvrT, b_qkvr, qbuf, kbuf, vTbuf, rbuf, nullptr, nullptr, nullptr);

    attn_kernel<<<dim3(SEQ / 64 * BATCH * HEADS), 256, 0, stream>>>(qbuf, kbuf, vTbuf, rbuf, attn_o);

    // PROJ: M=8192, N=768 -> 32 x 6 = 192 blocks
    gemmsb_kernel<EPI_PROJ, 768, 12, 6><<<192, 512, 0, stream>>>(
        attn_o, wprojT, b_proj, nullptr, nullptr, nullptr, nullptr, x, res, nullptr);
    ln_kernel<<<2048, 256, 0, stream>>>(res, ln1_g, ln1_b, x1f, x1b);

    // FF1+GELU: M=8192, N=3072
    gemmsb_kernel<EPI_GELU, 768, 12, 24><<<768, 512, 0, stream>>>(
        x1b, wff1T, b_ff1, nullptr, nullptr, nullptr, nullptr, nullptr, nullptr, ff1);

    // FF2: M=8192, N=768, K=3072 (48 K-tiles, 192 blocks — L2-friendly,
    // proven <=63us; split-K x4 regressed via +150MB partial traffic)
    gemmsb_kernel<EPI_FF2, 3072, 48, 6><<<192, 512, 0, stream>>>(
        ff1, wff2T, b_ff2, nullptr, nullptr, nullptr, nullptr, x1f, res, nullptr);
    ln_kernel<<<2048, 256, 0, stream>>>(res, ln2_g, ln2_b, out, nullptr);

    (void)in_sizes; (void)n_in; (void)out_size; (void)ws_size;
}